// Round 4
// baseline (258.842 us; speedup 1.0000x reference)
//
#include <hip/hip_runtime.h>
#include <math.h>

#define T_STEPS 256
#define BS      512
#define N       2048
#define BLOCK   128               // 2 waves per batch element
#define NWAVE   (BLOCK / 64)      // 2
#define EPT     (N / BLOCK)       // 16 elements per thread -> ~100 VGPRs, no spill
#define FUDGE   1e-4f

// --- wave64 sum via DPP: after this chain lane 63 holds the wave total ---
template <int CTRL>
__device__ __forceinline__ float dpp_add(float v) {
    int sh = __builtin_amdgcn_update_dpp(0, __float_as_int(v), CTRL, 0xf, 0xf, true);
    return v + __int_as_float(sh);
}

__device__ __forceinline__ float wave_sum_lane63(float v) {
    v = dpp_add<0x111>(v);  // row_shr:1
    v = dpp_add<0x112>(v);  // row_shr:2
    v = dpp_add<0x114>(v);  // row_shr:4
    v = dpp_add<0x118>(v);  // row_shr:8
    v = dpp_add<0x142>(v);  // row_bcast:15
    v = dpp_add<0x143>(v);  // row_bcast:31
    return v;               // total valid in lane 63
}

// One 2-wave block per batch element. Per step: in-wave DPP reduce of the
// fused pair (sum w_out*h, sum h*h), 2-wave combine through parity
// double-buffered LDS with a single __syncthreads per step.
// w_out kept scaled: w_t = sp_t * v_t, sp_t = wd^t  =>  update is one fma.
__global__ __launch_bounds__(BLOCK, 1)
void legacy_elbo_scan_kernel(
    const float* __restrict__ noises,   // [T, BS]
    const float* __restrict__ ys,       // [T]
    const float* __restrict__ qs,       // [T]
    const float* __restrict__ z_biases, // [N]
    const float* __restrict__ w_in,     // [N]
    const float* __restrict__ w_inq,    // [N]
    const float* __restrict__ p_llr,
    const float* __restrict__ p_llrd,
    const float* __restrict__ p_sigb,
    const float* __restrict__ p_oscale,
    const float* __restrict__ p_ufs,
    const float* __restrict__ p_lwd,
    const float* __restrict__ p_qscale,
    const float* __restrict__ p_tauq,
    const float* __restrict__ p_tauy,
    float* __restrict__ out)            // [T, BS]
{
    const int tid  = threadIdx.x;
    const int lane = tid & 63;
    const int wid  = tid >> 6;          // 0..1
    const int blk  = blockIdx.x;        // batch index k

    __shared__ float ys_s[T_STEPS];
    __shared__ float qs_s[T_STEPS];
    __shared__ float nz_s[T_STEPS];
    __shared__ float red[2][4];         // [parity][wave*2 + {su,sh2}]

#pragma unroll 2
    for (int i = 0; i < T_STEPS / BLOCK; ++i) {
        const int t = tid + i * BLOCK;
        ys_s[t] = ys[t];
        qs_s[t] = qs[t];
        nz_s[t] = noises[t * BS + blk];
    }

    const float llr     = p_llr[0];
    const float llrd    = p_llrd[0];
    const float sigb    = p_sigb[0];
    const float oscale  = p_oscale[0];
    const float ufs     = p_ufs[0];
    const float lwd     = p_lwd[0];
    const float qscale  = p_qscale[0];
    const float tauq_m1 = p_tauq[0];
    const float tauy_m1 = p_tauy[0];

    const float lr0      = expf(llr);
    const float lr_decay = expf(llrd);
    const float wd       = expf(lwd);
    const float rwd      = 1.0f / wd;
    const float tauq     = 1.0f + log1pf(expf(tauq_m1));
    const float tauy     = 1.0f + log1pf(expf(tauy_m1));
    const float omtq     = 1.0f - tauq;
    const float omty     = 1.0f - tauy;

    // Persistent per-thread state: 16 feature lanes, coalesced. 64 VGPRs.
    float v[EPT], bias[EPT], win[EPT], winq[EPT];
#pragma unroll 16
    for (int i = 0; i < EPT; ++i) {
        const int j = tid + i * BLOCK;
        bias[i] = sigb * z_biases[j];
        win[i]  = w_in[j];
        winq[i] = w_inq[j];
        v[i]    = 0.0f;
    }

    float u = 0.0f, e = 0.0f, lr_mult = 1.0f, qlp = 0.0f, ylp = 0.0f;
    float sp = 1.0f, rsp = 1.0f;        // wd^t and 1/wd^t

    __syncthreads();                    // staging visible to both waves

    float q_c = qs_s[0], y_c = ys_s[0], n_c = nz_s[0];

    for (int t = 0; t < T_STEPS; ++t) {
        const int tn = (t + 1 < T_STEPS) ? t + 1 : t;
        const float q_n = qs_s[tn], y_n = ys_s[tn], n_n = nz_s[tn];

        qlp = omtq * qlp + tauq * q_c;
        const float qsc = qscale * qlp;
        const float x   = fmaf(u, ufs, e) + n_c;

        float su[4] = {0.f, 0.f, 0.f, 0.f};
        float sh[4] = {0.f, 0.f, 0.f, 0.f};
        float h[EPT];
#pragma unroll 16
        for (int i = 0; i < EPT; ++i) {
            float hv = fmaf(x, win[i], fmaf(winq[i], qsc, bias[i]));
            hv = fmaxf(hv, 0.0f);
            h[i] = hv;
            su[i & 3] = fmaf(v[i], hv, su[i & 3]);
            sh[i & 3] = fmaf(hv, hv, sh[i & 3]);
        }
        float su_w = wave_sum_lane63((su[0] + su[1]) + (su[2] + su[3]));
        float sh_w = wave_sum_lane63((sh[0] + sh[1]) + (sh[2] + sh[3]));

        const int p = t & 1;
        if (lane == 63) {
            red[p][wid * 2]     = su_w;
            red[p][wid * 2 + 1] = sh_w;
        }
        __syncthreads();                // single barrier per step (parity-safe)
        const float4 rr = *(const float4*)&red[p][0];   // broadcast read
        const float su_t = rr.x + rr.z;
        const float sh2  = rr.y + rr.w;

        u = sp * su_t;                  // w_t = sp * v_t
        if (tid == 0) out[t * BS + blk] = oscale * u;

        ylp = omty * ylp + tauy * y_c;
        e = ylp - u;
        const float el = e * (lr0 * lr_mult);
        const float c  = el * rsp;      // dw coefficient in v-space

#pragma unroll 16
        for (int i = 0; i < EPT; ++i)
            v[i] = fmaf(c, h[i], v[i]);

        const float nrm = sqrtf(fmaf(el * el, sh2, FUDGE));
        lr_mult *= expf(-lr_decay * nrm);
        sp  *= wd;
        rsp *= rwd;

        q_c = q_n; y_c = y_n; n_c = n_n;
    }
}

extern "C" void kernel_launch(void* const* d_in, const int* in_sizes, int n_in,
                              void* d_out, int out_size, void* d_ws, size_t ws_size,
                              hipStream_t stream) {
    (void)in_sizes; (void)n_in; (void)d_ws; (void)ws_size; (void)out_size;
    const float* noises   = (const float*)d_in[0];
    const float* ys       = (const float*)d_in[1];
    const float* qs       = (const float*)d_in[2];
    const float* z_biases = (const float*)d_in[3];
    const float* w_in     = (const float*)d_in[4];
    const float* w_inq    = (const float*)d_in[5];
    const float* llr      = (const float*)d_in[6];
    const float* llrd     = (const float*)d_in[7];
    const float* sigb     = (const float*)d_in[8];
    const float* oscale   = (const float*)d_in[9];
    const float* ufs      = (const float*)d_in[10];
    const float* lwd      = (const float*)d_in[11];
    const float* qscale   = (const float*)d_in[12];
    const float* tauq     = (const float*)d_in[13];
    const float* tauy     = (const float*)d_in[14];
    float* out = (float*)d_out;

    hipLaunchKernelGGL(legacy_elbo_scan_kernel, dim3(BS), dim3(BLOCK), 0, stream,
                       noises, ys, qs, z_biases, w_in, w_inq,
                       llr, llrd, sigb, oscale, ufs, lwd, qscale, tauq, tauy,
                       out);
}

// Round 5
// 237.039 us; speedup vs baseline: 1.0920x; 1.0920x over previous
//
#include <hip/hip_runtime.h>
#include <math.h>

#define T_STEPS 256
#define BS      512
#define N       2048
#define WAVE    64
#define EPT     (N / WAVE)    // 32 elements per thread
#define FUDGE   1e-4f

// Force values to stay resident in VGPRs: the empty asm makes them opaque so
// the compiler cannot rematerialize them by re-loading from global memory
// inside the scan loop (which is what it did in R3/R4: VGPR_Count 96/56 <<
// live state, ~96 L1 reloads per step with no co-resident waves to hide them).
#define PIN8(A, B) asm volatile("" \
    : "+v"((A)[(B)+0]), "+v"((A)[(B)+1]), "+v"((A)[(B)+2]), "+v"((A)[(B)+3]), \
      "+v"((A)[(B)+4]), "+v"((A)[(B)+5]), "+v"((A)[(B)+6]), "+v"((A)[(B)+7]))
#define PIN32(A) do { PIN8(A,0); PIN8(A,8); PIN8(A,16); PIN8(A,24); } while (0)

// --- wave64 all-lanes sum via DPP ---------------------------------------
template <int CTRL>
__device__ __forceinline__ float dpp_add(float v) {
    int sh = __builtin_amdgcn_update_dpp(0, __float_as_int(v), CTRL, 0xf, 0xf, true);
    return v + __int_as_float(sh);
}

__device__ __forceinline__ float wave_allsum(float v) {
    v = dpp_add<0x111>(v);  // row_shr:1
    v = dpp_add<0x112>(v);  // row_shr:2
    v = dpp_add<0x114>(v);  // row_shr:4
    v = dpp_add<0x118>(v);  // row_shr:8
    v = dpp_add<0x142>(v);  // row_bcast:15
    v = dpp_add<0x143>(v);  // row_bcast:31
    return __int_as_float(__builtin_amdgcn_readlane(__float_as_int(v), 63));
}

// One wave per batch element; no barriers in the scan loop; all state in
// registers. w_out kept scaled: w_t = sp_t * v_t with sp_t = wd^t, so the
// per-element update is a single fma. norms = sqrt(FUDGE + (e*lr)^2 * sum h^2).
__global__ __launch_bounds__(WAVE, 1)
void legacy_elbo_scan_kernel(
    const float* __restrict__ noises,   // [T, BS]
    const float* __restrict__ ys,       // [T]
    const float* __restrict__ qs,       // [T]
    const float* __restrict__ z_biases, // [N]
    const float* __restrict__ w_in,     // [N]
    const float* __restrict__ w_inq,    // [N]
    const float* __restrict__ p_llr,
    const float* __restrict__ p_llrd,
    const float* __restrict__ p_sigb,
    const float* __restrict__ p_oscale,
    const float* __restrict__ p_ufs,
    const float* __restrict__ p_lwd,
    const float* __restrict__ p_qscale,
    const float* __restrict__ p_tauq,
    const float* __restrict__ p_tauy,
    float* __restrict__ out)            // [T, BS]
{
    const int lane = threadIdx.x;       // 0..63
    const int blk  = blockIdx.x;        // batch index k

    __shared__ float ys_s[T_STEPS];
    __shared__ float qs_s[T_STEPS];
    __shared__ float nz_s[T_STEPS];

#pragma unroll
    for (int i = 0; i < T_STEPS / WAVE; ++i) {
        const int t = lane + (i << 6);
        ys_s[t] = ys[t];
        qs_s[t] = qs[t];
        nz_s[t] = noises[t * BS + blk];
    }

    const float llr     = p_llr[0];
    const float llrd    = p_llrd[0];
    const float sigb    = p_sigb[0];
    const float oscale  = p_oscale[0];
    const float ufs     = p_ufs[0];
    const float lwd     = p_lwd[0];
    const float qscale  = p_qscale[0];
    const float tauq_m1 = p_tauq[0];
    const float tauy_m1 = p_tauy[0];

    const float lr0      = expf(llr);
    const float lr_decay = expf(llrd);
    const float wd       = expf(lwd);
    const float rwd      = 1.0f / wd;
    const float tauq     = 1.0f + log1pf(expf(tauq_m1));
    const float tauy     = 1.0f + log1pf(expf(tauy_m1));
    const float omtq     = 1.0f - tauq;
    const float omty     = 1.0f - tauy;

    // Persistent per-thread state: 32 feature lanes each, coalesced loads.
    float v[EPT], bias[EPT], win[EPT], winq[EPT];
#pragma unroll
    for (int i = 0; i < EPT; ++i) {
        const int j = lane + i * WAVE;
        bias[i] = sigb * z_biases[j];
        win[i]  = w_in[j];
        winq[i] = w_inq[j];
        v[i]    = 0.0f;
    }
    // Pin coefficients into VGPRs (prevents in-loop rematerialization).
    PIN32(bias); PIN32(win); PIN32(winq);

    float u = 0.0f, e = 0.0f, lr_mult = 1.0f, qlp = 0.0f, ylp = 0.0f;
    float sp = 1.0f, rsp = 1.0f;        // wd^t and 1/wd^t

    __syncthreads();                    // drain staging (single wave)

    float q_c = qs_s[0], y_c = ys_s[0], n_c = nz_s[0];

    for (int t = 0; t < T_STEPS; ++t) {
        const int tn = (t + 1 < T_STEPS) ? t + 1 : t;
        const float q_n = qs_s[tn], y_n = ys_s[tn], n_n = nz_s[tn];

        qlp = omtq * qlp + tauq * q_c;
        const float qsc = qscale * qlp;
        const float x   = fmaf(u, ufs, e) + n_c;

        float su[4] = {0.f, 0.f, 0.f, 0.f};
        float sh[4] = {0.f, 0.f, 0.f, 0.f};
        float h[EPT];
#pragma unroll
        for (int i = 0; i < EPT; ++i) {
            float hv = fmaf(x, win[i], fmaf(winq[i], qsc, bias[i]));
            hv = fmaxf(hv, 0.0f);
            h[i] = hv;
            su[i & 3] = fmaf(v[i], hv, su[i & 3]);
            sh[i & 3] = fmaf(hv, hv, sh[i & 3]);
        }
        const float su_t = wave_allsum((su[0] + su[1]) + (su[2] + su[3]));
        const float sh2  = wave_allsum((sh[0] + sh[1]) + (sh[2] + sh[3]));

        u = sp * su_t;                  // w_t = sp * v_t
        if (lane == 0) out[t * BS + blk] = oscale * u;

        ylp = omty * ylp + tauy * y_c;
        e = ylp - u;
        const float el = e * (lr0 * lr_mult);
        const float c  = el * rsp;      // dw coefficient in v-space

#pragma unroll
        for (int i = 0; i < EPT; ++i)
            v[i] = fmaf(c, h[i], v[i]);

        const float nrm = sqrtf(fmaf(el * el, sh2, FUDGE));
        lr_mult *= expf(-lr_decay * nrm);
        sp  *= wd;
        rsp *= rwd;

        q_c = q_n; y_c = y_n; n_c = n_n;
    }
}

extern "C" void kernel_launch(void* const* d_in, const int* in_sizes, int n_in,
                              void* d_out, int out_size, void* d_ws, size_t ws_size,
                              hipStream_t stream) {
    (void)in_sizes; (void)n_in; (void)d_ws; (void)ws_size; (void)out_size;
    const float* noises   = (const float*)d_in[0];
    const float* ys       = (const float*)d_in[1];
    const float* qs       = (const float*)d_in[2];
    const float* z_biases = (const float*)d_in[3];
    const float* w_in     = (const float*)d_in[4];
    const float* w_inq    = (const float*)d_in[5];
    const float* llr      = (const float*)d_in[6];
    const float* llrd     = (const float*)d_in[7];
    const float* sigb     = (const float*)d_in[8];
    const float* oscale   = (const float*)d_in[9];
    const float* ufs      = (const float*)d_in[10];
    const float* lwd      = (const float*)d_in[11];
    const float* qscale   = (const float*)d_in[12];
    const float* tauq     = (const float*)d_in[13];
    const float* tauy     = (const float*)d_in[14];
    float* out = (float*)d_out;

    hipLaunchKernelGGL(legacy_elbo_scan_kernel, dim3(BS), dim3(WAVE), 0, stream,
                       noises, ys, qs, z_biases, w_in, w_inq,
                       llr, llrd, sigb, oscale, ufs, lwd, qscale, tauq, tauy,
                       out);
}